// Round 5
// baseline (417.920 us; speedup 1.0000x reference)
//
#include <hip/hip_runtime.h>
#include <hip/hip_fp16.h>

typedef _Float16 f16;
typedef _Float16 f16x4 __attribute__((ext_vector_type(4)));
typedef _Float16 f16x8 __attribute__((ext_vector_type(8)));
typedef float f32x4 __attribute__((ext_vector_type(4)));
typedef float f32x16 __attribute__((ext_vector_type(16)));
typedef unsigned int u32;
typedef u32 u32x4 __attribute__((ext_vector_type(4)));

static constexpr int CB = 8;      // batch
static constexpr int CC = 256;    // channels = Co
static constexpr int CN = 4096;   // tokens = H*W
static constexpr float LOG2E = 1.44269504088896f;

#define MFMA(a, b, c)   __builtin_amdgcn_mfma_f32_16x16x32_f16((a), (b), (c), 0, 0, 0)
#define MFMA32(a, b, c) __builtin_amdgcn_mfma_f32_32x32x16_f16((a), (b), (c), 0, 0, 0)

__device__ __forceinline__ void gll16(const void* g, void* l) {
  __builtin_amdgcn_global_load_lds(
      (const __attribute__((address_space(1))) unsigned int*)g,
      (__attribute__((address_space(3))) unsigned int*)l, 16, 0, 0);
}

// swap a's lanes 32-63 with b's lanes 0-31 (CDNA4 cross-half exchange)
__device__ __forceinline__ void plswap(u32& a, u32& b) {
  asm volatile("v_permlane32_swap_b32 %0, %1" : "+v"(a), "+v"(b));
}

__device__ __forceinline__ u32 pk(float lo, float hi) {
  auto h = __builtin_amdgcn_cvt_pkrtz(lo, hi);   // __fp16 ext_vector_type(2)
  return __builtin_bit_cast(u32, h);
}

__global__ __launch_bounds__(256) void prep_weights(const float* __restrict__ wq,
    const float* __restrict__ wk, const float* __restrict__ wv,
    const float* __restrict__ wo, f16* __restrict__ W) {
  int i = blockIdx.x * 256 + threadIdx.x;
  W[i]          = (f16)wq[i];
  W[65536 + i]  = (f16)wk[i];
  W[131072 + i] = (f16)wv[i];
  W[196608 + i] = (f16)wo[i];
}

// x [B,C,N] fp32  ->  Q,K [B,N,256] f16 ; V^T [B,256,N] f16   (unchanged, verified)
__global__ __launch_bounds__(256) void qkv_kernel(const float* __restrict__ x,
    const f16* __restrict__ Wq, const f16* __restrict__ Wk, const f16* __restrict__ Wv,
    const float* __restrict__ bq, const float* __restrict__ bk, const float* __restrict__ bv,
    f16* __restrict__ Q, f16* __restrict__ K, f16* __restrict__ Vt) {
  __shared__ f16 xf[64][264];
  const int b  = blockIdx.x >> 6;
  const int n0 = (blockIdx.x & 63) << 6;
  const int t  = threadIdx.x;
  const float* xb = x + (size_t)b * CC * CN;
  {
    int c = t >> 4;
    const int nn = (t & 15) << 2;
    #pragma unroll
    for (int pass = 0; pass < 16; ++pass, c += 16) {
      const float4 v = *(const float4*)(xb + (size_t)c * CN + n0 + nn);
      xf[nn + 0][c] = (f16)v.x;
      xf[nn + 1][c] = (f16)v.y;
      xf[nn + 2][c] = (f16)v.z;
      xf[nn + 3][c] = (f16)v.w;
    }
  }
  __syncthreads();
  const int w = t >> 6, l = t & 63, lr = l & 15, lh = l >> 4;

  f16x8 xff[8];
  #pragma unroll
  for (int kk = 0; kk < 8; ++kk)
    xff[kk] = *(const f16x8*)&xf[w * 16 + lr][kk * 32 + lh * 8];

  const size_t qkrow = ((size_t)b * CN + n0 + w * 16 + lr) * CC;

  #pragma unroll 1
  for (int mat = 0; mat < 2; ++mat) {
    const f16* W = mat ? Wk : Wq;
    const float* bias = mat ? bk : bq;
    f16* dst = mat ? K : Q;
    f32x4 acc[16];
    #pragma unroll
    for (int m = 0; m < 16; ++m) acc[m] = f32x4{0.f, 0.f, 0.f, 0.f};
    #pragma unroll
    for (int kk = 0; kk < 8; ++kk) {
      #pragma unroll
      for (int m = 0; m < 16; ++m) {
        f16x8 af = *(const f16x8*)&W[(size_t)(m * 16 + lr) * CC + kk * 32 + lh * 8];
        acc[m] = MFMA(af, xff[kk], acc[m]);
      }
    }
    #pragma unroll
    for (int m = 0; m < 16; ++m) {
      const int o = m * 16 + lh * 4;
      const float4 bs = *(const float4*)&bias[o];
      f16x4 hv;
      hv[0] = (f16)(acc[m][0] + bs.x);
      hv[1] = (f16)(acc[m][1] + bs.y);
      hv[2] = (f16)(acc[m][2] + bs.z);
      hv[3] = (f16)(acc[m][3] + bs.w);
      *(f16x4*)&dst[qkrow + o] = hv;
    }
  }
  {
    f32x4 acc[16];
    #pragma unroll
    for (int m = 0; m < 16; ++m) acc[m] = f32x4{0.f, 0.f, 0.f, 0.f};
    #pragma unroll
    for (int kk = 0; kk < 8; ++kk) {
      #pragma unroll
      for (int m = 0; m < 16; ++m) {
        f16x8 bf = *(const f16x8*)&Wv[(size_t)(m * 16 + lr) * CC + kk * 32 + lh * 8];
        acc[m] = MFMA(xff[kk], bf, acc[m]);
      }
    }
    #pragma unroll
    for (int m = 0; m < 16; ++m) {
      const int o = m * 16 + lr;
      const float bvs = bv[o];
      f16x4 hv;
      #pragma unroll
      for (int j = 0; j < 4; ++j) hv[j] = (f16)(acc[m][j] + bvs);
      *(f16x4*)&Vt[((size_t)b * CC + o) * CN + n0 + w * 16 + lh * 4] = hv;
    }
  }
}

// flash attention v4: 32x32x16 MFMA, 4 waves = 2 q-groups x 2 o-halves, 64 q/block,
// grid 512 -> 2 independent blocks/CU (decoupled barriers). K/V frag-linear frames
// via global_load_lds; P relayout fully in-register (cvt_pkrtz + permlane32_swap).
// Q,K [B,N,256], V^T [B,256,N] -> O [B,N,256]
__global__ __launch_bounds__(256, 2) void attn_kernel(const f16* __restrict__ Q,
    const f16* __restrict__ K, const f16* __restrict__ Vt, f16* __restrict__ O) {
  // SMEM (bytes):
  //   [0, 65536): K/V frames: buf*32768 + frame*1024; frames 0..15 = K(ks),
  //               16..31 = V(f: o-block f>>1, kv-half f&1). Frag-linear (+16*l).
  //   [65536, 66048): per-wave alpha/inv floats: w*128
  __shared__ __align__(16) char SMEM[66048];

  const int bid = blockIdx.x;
  const int lb = ((bid & 7) << 6) | (bid >> 3);   // XCD swizzle: batch -> XCD (512 = 8x64)
  const int b  = lb >> 6;
  const int q0 = (lb & 63) << 6;                  // 64 q-rows per block
  const int t  = threadIdx.x;
  const int w  = t >> 6, l = t & 63, ln = l & 31, lh = l >> 5;
  const int g  = w >> 1, hv = w & 1;              // q-group, o-half

  const f16* Qb = Q  + (size_t)b * CN * CC;
  const f16* Kb = K  + (size_t)b * CN * CC;
  const f16* Vb = Vt + (size_t)b * CC * CN;

  float* const ALf = (float*)(SMEM + 65536 + w * 128);

  // stage one 32-kv tile: each wave stages 4 K frames + 4 V frames (8 x gll16)
  auto stage = [&](int buf, int kv0) {
    char* base = SMEM + (buf << 15);
    const f16* ksrc = Kb + (size_t)(kv0 + ln) * CC + (w * 4) * 16 + 8 * lh;
    #pragma unroll
    for (int j = 0; j < 4; ++j)
      gll16(ksrc + j * 16, base + ((w * 4 + j) << 10));
    #pragma unroll
    for (int p = 0; p < 2; ++p) {
      const int f = w * 4 + 2 * p;                // o-block f>>1 = 2w+p
      const f16* vsrc = Vb + (size_t)((f >> 1) * 32 + ln) * CN + kv0 + 8 * lh;
      gll16(vsrc,      base + ((16 + f)     << 10));
      gll16(vsrc + 16, base + ((16 + f + 1) << 10));
    }
  };

  // Q fragments in registers: B-operand of swapped QK^T (lane: q=ln, c=16ks+8lh+e)
  const int qrow = q0 + 32 * g + ln;
  f16x8 qf[16];
  #pragma unroll
  for (int ks = 0; ks < 16; ++ks)
    qf[ks] = *(const f16x8*)(Qb + (size_t)qrow * CC + ks * 16 + 8 * lh);

  f32x16 oacc[4];
  #pragma unroll
  for (int ot = 0; ot < 4; ++ot)
    #pragma unroll
    for (int i = 0; i < 16; ++i) oacc[ot][i] = 0.0f;
  float mrun = -3e38f, lrun = 0.0f;

  stage(0, 0);
  __syncthreads();

  for (int it = 0; it < 128; ++it) {
    const int cur = it & 1;
    if (it < 127) stage(cur ^ 1, (it + 1) * 32);   // async prefetch, drained at barrier

    // swapped QK^T: S^T[kv][q]; A=K frag (lane: kv=ln, c=16ks+8lh+e), B=Q frag
    f32x16 s;
    #pragma unroll
    for (int i = 0; i < 16; ++i) s[i] = 0.0f;
    #pragma unroll
    for (int ks = 0; ks < 16; ++ks) {
      const f16x8 kf = *(const f16x8*)(SMEM + (cur << 15) + (ks << 10) + l * 16);
      s = MFMA32(kf, qf[ks], s);
    }

    // online softmax: lane owns q=ln; 16 kv in-lane, partner (l^32) has other 16
    float pmax = -3e38f;
    #pragma unroll
    for (int r = 0; r < 16; ++r) pmax = fmaxf(pmax, s[r]);
    pmax = fmaxf(pmax, __shfl_xor(pmax, 32));
    const bool need = !__all(pmax - mrun <= 8.0f);      // defer-max (T13)
    float mnew = mrun;
    if (need) mnew = fmaxf(mrun, pmax);
    float psum = 0.0f;
    float p[16];
    #pragma unroll
    for (int r = 0; r < 16; ++r) {
      p[r] = exp2f((s[r] - mnew) * LOG2E);
      psum += p[r];
    }
    psum += __shfl_xor(psum, 32);
    if (need) {                                          // rare rescale path
      const float alpha = exp2f((mrun - mnew) * LOG2E);
      lrun = lrun * alpha + psum;
      mrun = mnew;
      if (l < 32) ALf[ln] = alpha;                       // lanes l, l^32 agree
      #pragma unroll
      for (int r = 0; r < 16; ++r) {
        const float fr = ALf[(r & 3) + 8 * (r >> 2) + 4 * lh];  // alpha of q(r)
        #pragma unroll
        for (int ot = 0; ot < 4; ++ot) oacc[ot][r] *= fr;
      }
    } else {
      lrun += psum;
    }

    // in-register P relayout: pack f32 pairs -> f16x2 words, cross-half swap.
    // After swap(pw0,pw2), swap(pw1,pw3): {pw0,pw1,pw2,pw3} is the A-frag for
    // kv-step 0 (cols 8*lh..8*lh+7), per the m74 32x32 C/D map.
    u32 pw[8];
    #pragma unroll
    for (int i = 0; i < 8; ++i) pw[i] = pk(p[2 * i], p[2 * i + 1]);
    plswap(pw[0], pw[2]); plswap(pw[1], pw[3]);          // kv 0..15
    plswap(pw[4], pw[6]); plswap(pw[5], pw[7]);          // kv 16..31
    const f16x8 pa0 = __builtin_bit_cast(f16x8, u32x4{pw[0], pw[1], pw[2], pw[3]});
    const f16x8 pa1 = __builtin_bit_cast(f16x8, u32x4{pw[4], pw[5], pw[6], pw[7]});

    // PV: D[q][o] += P x V; B=V frag (lane: o=ln, kv=8lh+e); own o-half only
    #pragma unroll
    for (int ot = 0; ot < 4; ++ot) {
      const int f0 = 16 + 8 * hv + 2 * ot;
      const f16x8 v0 = *(const f16x8*)(SMEM + (cur << 15) + (f0 << 10) + l * 16);
      oacc[ot] = MFMA32(pa0, v0, oacc[ot]);
      const f16x8 v1 = *(const f16x8*)(SMEM + (cur << 15) + ((f0 + 1) << 10) + l * 16);
      oacc[ot] = MFMA32(pa1, v1, oacc[ot]);
    }
    __syncthreads();
  }

  // epilogue: direct store of own 32q x 128o slice, scaled by 1/l
  if (l < 32) ALf[ln] = 1.0f / lrun;
  f16* Ob = O + ((size_t)b * CN + q0 + 32 * g) * CC + 128 * hv;
  #pragma unroll
  for (int r = 0; r < 16; ++r) {
    const int q = (r & 3) + 8 * (r >> 2) + 4 * lh;
    const float inv = ALf[q];
    #pragma unroll
    for (int ot = 0; ot < 4; ++ot)
      Ob[(size_t)q * CC + ot * 32 + ln] = (f16)(oacc[ot][r] * inv);
  }
}

// out[b,c,n] = sum_o O[b,n,o] * Wo[c,o] + bo[c]   (unchanged, verified)
__global__ __launch_bounds__(256) void oproj_kernel(const f16* __restrict__ O,
    const f16* __restrict__ Wo, const float* __restrict__ bo, float* __restrict__ out) {
  const int b  = blockIdx.x >> 6;
  const int n0 = (blockIdx.x & 63) << 6;
  const int t  = threadIdx.x;
  const int w = t >> 6, l = t & 63, lr = l & 15, lh = l >> 4;
  const f16* orow = O + ((size_t)b * CN + n0 + w * 16 + lr) * CC;
  f32x4 acc[16];
  #pragma unroll
  for (int m = 0; m < 16; ++m) acc[m] = f32x4{0.f, 0.f, 0.f, 0.f};
  #pragma unroll
  for (int kk = 0; kk < 8; ++kk) {
    const f16x8 bf = *(const f16x8*)&orow[kk * 32 + lh * 8];
    #pragma unroll
    for (int m = 0; m < 16; ++m) {
      f16x8 af = *(const f16x8*)&Wo[(size_t)(m * 16 + lr) * CC + kk * 32 + lh * 8];
      acc[m] = MFMA(af, bf, acc[m]);
    }
  }
  #pragma unroll
  for (int m = 0; m < 16; ++m) {
    const int c = m * 16 + lh * 4;
    const float4 bv4 = *(const float4*)&bo[c];
    const size_t base = ((size_t)b * CC + c) * CN + n0 + w * 16 + lr;
    out[base + 0 * (size_t)CN] = acc[m][0] + bv4.x;
    out[base + 1 * (size_t)CN] = acc[m][1] + bv4.y;
    out[base + 2 * (size_t)CN] = acc[m][2] + bv4.z;
    out[base + 3 * (size_t)CN] = acc[m][3] + bv4.w;
  }
}

extern "C" void kernel_launch(void* const* d_in, const int* in_sizes, int n_in,
                              void* d_out, int out_size, void* d_ws, size_t ws_size,
                              hipStream_t stream) {
  const float* x  = (const float*)d_in[0];
  const float* wq = (const float*)d_in[1];
  const float* bq = (const float*)d_in[2];
  const float* wk = (const float*)d_in[3];
  const float* bk = (const float*)d_in[4];
  const float* wv = (const float*)d_in[5];
  const float* bv = (const float*)d_in[6];
  const float* wo = (const float*)d_in[7];
  const float* bo = (const float*)d_in[8];

  f16* W  = (f16*)d_ws;                     // 4 x 65536 f16 weights
  f16* Qd = W + 262144;                     // [B,N,256]
  f16* Kd = Qd + (size_t)CB * CN * CC;      // [B,N,256]
  f16* Vt = Kd + (size_t)CB * CN * CC;      // [B,256,N]
  f16* Od = Vt + (size_t)CB * CN * CC;      // [B,N,256]

  prep_weights<<<256, 256, 0, stream>>>(wq, wk, wv, wo, W);
  qkv_kernel<<<512, 256, 0, stream>>>(x, W, W + 65536, W + 131072, bq, bk, bv, Qd, Kd, Vt);
  attn_kernel<<<512, 256, 0, stream>>>(Qd, Kd, Vt, Od);
  oproj_kernel<<<512, 256, 0, stream>>>(Od, W + 196608, bo, (float*)d_out);
}

// Round 6
// 404.595 us; speedup vs baseline: 1.0329x; 1.0329x over previous
//
#include <hip/hip_runtime.h>
#include <hip/hip_fp16.h>

typedef _Float16 f16;
typedef _Float16 f16x4 __attribute__((ext_vector_type(4)));
typedef _Float16 f16x8 __attribute__((ext_vector_type(8)));
typedef float f32x4 __attribute__((ext_vector_type(4)));
typedef float f32x16 __attribute__((ext_vector_type(16)));
typedef unsigned int u32;
typedef u32 u32x4 __attribute__((ext_vector_type(4)));

static constexpr int CB = 8;      // batch
static constexpr int CC = 256;    // channels = Co
static constexpr int CN = 4096;   // tokens = H*W

#define MFMA(a, b, c)   __builtin_amdgcn_mfma_f32_16x16x32_f16((a), (b), (c), 0, 0, 0)
#define MFMA32(a, b, c) __builtin_amdgcn_mfma_f32_32x32x16_f16((a), (b), (c), 0, 0, 0)

__device__ __forceinline__ void gll16(const void* g, void* l) {
  __builtin_amdgcn_global_load_lds(
      (const __attribute__((address_space(1))) unsigned int*)g,
      (__attribute__((address_space(3))) unsigned int*)l, 16, 0, 0);
}

// swap a's lanes 32-63 with b's lanes 0-31 (CDNA4 cross-half exchange)
__device__ __forceinline__ void plswap(u32& a, u32& b) {
  asm volatile("v_permlane32_swap_b32 %0, %1" : "+v"(a), "+v"(b));
}

__device__ __forceinline__ u32 pk(float lo, float hi) {
  auto h = __builtin_amdgcn_cvt_pkrtz(lo, hi);   // __fp16 ext_vector_type(2)
  return __builtin_bit_cast(u32, h);
}

__global__ __launch_bounds__(256) void prep_weights(const float* __restrict__ wq,
    const float* __restrict__ wk, const float* __restrict__ wv,
    const float* __restrict__ wo, f16* __restrict__ W) {
  int i = blockIdx.x * 256 + threadIdx.x;
  W[i]          = (f16)wq[i];
  W[65536 + i]  = (f16)wk[i];
  W[131072 + i] = (f16)wv[i];
  W[196608 + i] = (f16)wo[i];
}

// x [B,C,N] fp32  ->  Q,K [B,N,256] f16 ; V^T [B,256,N] f16   (unchanged, verified)
__global__ __launch_bounds__(256) void qkv_kernel(const float* __restrict__ x,
    const f16* __restrict__ Wq, const f16* __restrict__ Wk, const f16* __restrict__ Wv,
    const float* __restrict__ bq, const float* __restrict__ bk, const float* __restrict__ bv,
    f16* __restrict__ Q, f16* __restrict__ K, f16* __restrict__ Vt) {
  __shared__ f16 xf[64][264];
  const int b  = blockIdx.x >> 6;
  const int n0 = (blockIdx.x & 63) << 6;
  const int t  = threadIdx.x;
  const float* xb = x + (size_t)b * CC * CN;
  {
    int c = t >> 4;
    const int nn = (t & 15) << 2;
    #pragma unroll
    for (int pass = 0; pass < 16; ++pass, c += 16) {
      const float4 v = *(const float4*)(xb + (size_t)c * CN + n0 + nn);
      xf[nn + 0][c] = (f16)v.x;
      xf[nn + 1][c] = (f16)v.y;
      xf[nn + 2][c] = (f16)v.z;
      xf[nn + 3][c] = (f16)v.w;
    }
  }
  __syncthreads();
  const int w = t >> 6, l = t & 63, lr = l & 15, lh = l >> 4;

  f16x8 xff[8];
  #pragma unroll
  for (int kk = 0; kk < 8; ++kk)
    xff[kk] = *(const f16x8*)&xf[w * 16 + lr][kk * 32 + lh * 8];

  const size_t qkrow = ((size_t)b * CN + n0 + w * 16 + lr) * CC;

  #pragma unroll 1
  for (int mat = 0; mat < 2; ++mat) {
    const f16* W = mat ? Wk : Wq;
    const float* bias = mat ? bk : bq;
    f16* dst = mat ? K : Q;
    f32x4 acc[16];
    #pragma unroll
    for (int m = 0; m < 16; ++m) acc[m] = f32x4{0.f, 0.f, 0.f, 0.f};
    #pragma unroll
    for (int kk = 0; kk < 8; ++kk) {
      #pragma unroll
      for (int m = 0; m < 16; ++m) {
        f16x8 af = *(const f16x8*)&W[(size_t)(m * 16 + lr) * CC + kk * 32 + lh * 8];
        acc[m] = MFMA(af, xff[kk], acc[m]);
      }
    }
    #pragma unroll
    for (int m = 0; m < 16; ++m) {
      const int o = m * 16 + lh * 4;
      const float4 bs = *(const float4*)&bias[o];
      f16x4 hv;
      hv[0] = (f16)(acc[m][0] + bs.x);
      hv[1] = (f16)(acc[m][1] + bs.y);
      hv[2] = (f16)(acc[m][2] + bs.z);
      hv[3] = (f16)(acc[m][3] + bs.w);
      *(f16x4*)&dst[qkrow + o] = hv;
    }
  }
  {
    f32x4 acc[16];
    #pragma unroll
    for (int m = 0; m < 16; ++m) acc[m] = f32x4{0.f, 0.f, 0.f, 0.f};
    #pragma unroll
    for (int kk = 0; kk < 8; ++kk) {
      #pragma unroll
      for (int m = 0; m < 16; ++m) {
        f16x8 bf = *(const f16x8*)&Wv[(size_t)(m * 16 + lr) * CC + kk * 32 + lh * 8];
        acc[m] = MFMA(xff[kk], bf, acc[m]);
      }
    }
    #pragma unroll
    for (int m = 0; m < 16; ++m) {
      const int o = m * 16 + lr;
      const float bvs = bv[o];
      f16x4 hv;
      #pragma unroll
      for (int j = 0; j < 4; ++j) hv[j] = (f16)(acc[m][j] + bvs);
      *(f16x4*)&Vt[((size_t)b * CC + o) * CN + n0 + w * 16 + lh * 4] = hv;
    }
  }
}

// flash attention v5: v4 structure + native v_exp_f32, tree reductions,
// dual QK^T MFMA chains, setprio around MFMA clusters.
// Q,K [B,N,256], V^T [B,256,N] -> O [B,N,256]
__global__ __launch_bounds__(256, 2) void attn_kernel(const f16* __restrict__ Q,
    const f16* __restrict__ K, const f16* __restrict__ Vt, f16* __restrict__ O) {
  // SMEM (bytes):
  //   [0, 65536): K/V frames: buf*32768 + frame*1024; frames 0..15 = K(ks),
  //               16..31 = V(f: o-block f>>1, kv-half f&1). Frag-linear (+16*l).
  //   [65536, 66048): per-wave alpha/inv floats: w*128
  __shared__ __align__(16) char SMEM[66048];

  const int bid = blockIdx.x;
  const int lb = ((bid & 7) << 6) | (bid >> 3);   // XCD swizzle: batch -> XCD (512 = 8x64)
  const int b  = lb >> 6;
  const int q0 = (lb & 63) << 6;                  // 64 q-rows per block
  const int t  = threadIdx.x;
  const int w  = t >> 6, l = t & 63, ln = l & 31, lh = l >> 5;
  const int g  = w >> 1, hv = w & 1;              // q-group, o-half

  const f16* Qb = Q  + (size_t)b * CN * CC;
  const f16* Kb = K  + (size_t)b * CN * CC;
  const f16* Vb = Vt + (size_t)b * CC * CN;

  float* const ALf = (float*)(SMEM + 65536 + w * 128);

  // stage one 32-kv tile: each wave stages 4 K frames + 4 V frames (8 x gll16)
  auto stage = [&](int buf, int kv0) {
    char* base = SMEM + (buf << 15);
    const f16* ksrc = Kb + (size_t)(kv0 + ln) * CC + (w * 4) * 16 + 8 * lh;
    #pragma unroll
    for (int j = 0; j < 4; ++j)
      gll16(ksrc + j * 16, base + ((w * 4 + j) << 10));
    #pragma unroll
    for (int p = 0; p < 2; ++p) {
      const int f = w * 4 + 2 * p;                // o-block f>>1 = 2w+p
      const f16* vsrc = Vb + (size_t)((f >> 1) * 32 + ln) * CN + kv0 + 8 * lh;
      gll16(vsrc,      base + ((16 + f)     << 10));
      gll16(vsrc + 16, base + ((16 + f + 1) << 10));
    }
  };

  // Q fragments in registers: B-operand of swapped QK^T (lane: q=ln, c=16ks+8lh+e)
  const int qrow = q0 + 32 * g + ln;
  f16x8 qf[16];
  #pragma unroll
  for (int ks = 0; ks < 16; ++ks)
    qf[ks] = *(const f16x8*)(Qb + (size_t)qrow * CC + ks * 16 + 8 * lh);

  f32x16 oacc[4];
  #pragma unroll
  for (int ot = 0; ot < 4; ++ot)
    #pragma unroll
    for (int i = 0; i < 16; ++i) oacc[ot][i] = 0.0f;
  float mrun = -3e38f, lrun = 0.0f;

  stage(0, 0);
  __syncthreads();

  for (int it = 0; it < 128; ++it) {
    const int cur = it & 1;
    if (it < 127) stage(cur ^ 1, (it + 1) * 32);   // async prefetch, drained at barrier

    // swapped QK^T: S^T[kv][q]; A=K frag (lane: kv=ln, c=16ks+8lh+e), B=Q frag.
    // Two independent 8-deep chains, interleaved.
    f32x16 s, s1;
    #pragma unroll
    for (int i = 0; i < 16; ++i) { s[i] = 0.0f; s1[i] = 0.0f; }
    __builtin_amdgcn_s_setprio(1);
    #pragma unroll
    for (int ks = 0; ks < 8; ++ks) {
      const f16x8 kf0 = *(const f16x8*)(SMEM + (cur << 15) + (ks << 10) + l * 16);
      s  = MFMA32(kf0, qf[ks], s);
      const f16x8 kf1 = *(const f16x8*)(SMEM + (cur << 15) + ((ks + 8) << 10) + l * 16);
      s1 = MFMA32(kf1, qf[ks + 8], s1);
    }
    __builtin_amdgcn_s_setprio(0);
    #pragma unroll
    for (int i = 0; i < 16; ++i) s[i] += s1[i];

    // online softmax: lane owns q=ln; 16 kv in-lane, partner (l^32) has other 16.
    // Tree-structured max (log depth; FP max is order-safe).
    float mx8[8], mx4[4];
    #pragma unroll
    for (int i = 0; i < 8; ++i) mx8[i] = fmaxf(s[2 * i], s[2 * i + 1]);
    #pragma unroll
    for (int i = 0; i < 4; ++i) mx4[i] = fmaxf(mx8[2 * i], mx8[2 * i + 1]);
    float pmax = fmaxf(fmaxf(mx4[0], mx4[1]), fmaxf(mx4[2], mx4[3]));
    pmax = fmaxf(pmax, __shfl_xor(pmax, 32));
    const bool need = !__all(pmax - mrun <= 8.0f);      // defer-max (T13)
    const float mnew = need ? fmaxf(mrun, pmax) : mrun;
    float p[16];
    #pragma unroll
    for (int r = 0; r < 16; ++r) p[r] = __expf(s[r] - mnew);  // native v_exp_f32
    // tree sum
    float sm8[8], sm4[4];
    #pragma unroll
    for (int i = 0; i < 8; ++i) sm8[i] = p[2 * i] + p[2 * i + 1];
    #pragma unroll
    for (int i = 0; i < 4; ++i) sm4[i] = sm8[2 * i] + sm8[2 * i + 1];
    float psum = (sm4[0] + sm4[1]) + (sm4[2] + sm4[3]);
    psum += __shfl_xor(psum, 32);
    if (need) {                                          // rare rescale path
      const float alpha = __expf(mrun - mnew);
      lrun = lrun * alpha + psum;
      mrun = mnew;
      if (l < 32) ALf[ln] = alpha;                       // lanes l, l^32 agree
      #pragma unroll
      for (int r = 0; r < 16; ++r) {
        const float fr = ALf[(r & 3) + 8 * (r >> 2) + 4 * lh];  // alpha of q(r)
        #pragma unroll
        for (int ot = 0; ot < 4; ++ot) oacc[ot][r] *= fr;
      }
    } else {
      lrun += psum;
    }

    // in-register P relayout: pack f32 pairs -> f16x2 words, cross-half swap.
    u32 pw[8];
    #pragma unroll
    for (int i = 0; i < 8; ++i) pw[i] = pk(p[2 * i], p[2 * i + 1]);
    plswap(pw[0], pw[2]); plswap(pw[1], pw[3]);          // kv 0..15
    plswap(pw[4], pw[6]); plswap(pw[5], pw[7]);          // kv 16..31
    const f16x8 pa0 = __builtin_bit_cast(f16x8, u32x4{pw[0], pw[1], pw[2], pw[3]});
    const f16x8 pa1 = __builtin_bit_cast(f16x8, u32x4{pw[4], pw[5], pw[6], pw[7]});

    // PV: D[q][o] += P x V; B=V frag (lane: o=ln, kv=8lh+e); own o-half only
    __builtin_amdgcn_s_setprio(1);
    #pragma unroll
    for (int ot = 0; ot < 4; ++ot) {
      const int f0 = 16 + 8 * hv + 2 * ot;
      const f16x8 v0 = *(const f16x8*)(SMEM + (cur << 15) + (f0 << 10) + l * 16);
      oacc[ot] = MFMA32(pa0, v0, oacc[ot]);
      const f16x8 v1 = *(const f16x8*)(SMEM + (cur << 15) + ((f0 + 1) << 10) + l * 16);
      oacc[ot] = MFMA32(pa1, v1, oacc[ot]);
    }
    __builtin_amdgcn_s_setprio(0);
    __syncthreads();
  }

  // epilogue: direct store of own 32q x 128o slice, scaled by 1/l
  if (l < 32) ALf[ln] = 1.0f / lrun;
  f16* Ob = O + ((size_t)b * CN + q0 + 32 * g) * CC + 128 * hv;
  #pragma unroll
  for (int r = 0; r < 16; ++r) {
    const int q = (r & 3) + 8 * (r >> 2) + 4 * lh;
    const float inv = ALf[q];
    #pragma unroll
    for (int ot = 0; ot < 4; ++ot)
      Ob[(size_t)q * CC + ot * 32 + ln] = (f16)(oacc[ot][r] * inv);
  }
}

// out[b,c,n] = sum_o O[b,n,o] * Wo[c,o] + bo[c]   (unchanged, verified)
__global__ __launch_bounds__(256) void oproj_kernel(const f16* __restrict__ O,
    const f16* __restrict__ Wo, const float* __restrict__ bo, float* __restrict__ out) {
  const int b  = blockIdx.x >> 6;
  const int n0 = (blockIdx.x & 63) << 6;
  const int t  = threadIdx.x;
  const int w = t >> 6, l = t & 63, lr = l & 15, lh = l >> 4;
  const f16* orow = O + ((size_t)b * CN + n0 + w * 16 + lr) * CC;
  f32x4 acc[16];
  #pragma unroll
  for (int m = 0; m < 16; ++m) acc[m] = f32x4{0.f, 0.f, 0.f, 0.f};
  #pragma unroll
  for (int kk = 0; kk < 8; ++kk) {
    const f16x8 bf = *(const f16x8*)&orow[kk * 32 + lh * 8];
    #pragma unroll
    for (int m = 0; m < 16; ++m) {
      f16x8 af = *(const f16x8*)&Wo[(size_t)(m * 16 + lr) * CC + kk * 32 + lh * 8];
      acc[m] = MFMA(af, bf, acc[m]);
    }
  }
  #pragma unroll
  for (int m = 0; m < 16; ++m) {
    const int c = m * 16 + lh * 4;
    const float4 bv4 = *(const float4*)&bo[c];
    const size_t base = ((size_t)b * CC + c) * CN + n0 + w * 16 + lr;
    out[base + 0 * (size_t)CN] = acc[m][0] + bv4.x;
    out[base + 1 * (size_t)CN] = acc[m][1] + bv4.y;
    out[base + 2 * (size_t)CN] = acc[m][2] + bv4.z;
    out[base + 3 * (size_t)CN] = acc[m][3] + bv4.w;
  }
}

extern "C" void kernel_launch(void* const* d_in, const int* in_sizes, int n_in,
                              void* d_out, int out_size, void* d_ws, size_t ws_size,
                              hipStream_t stream) {
  const float* x  = (const float*)d_in[0];
  const float* wq = (const float*)d_in[1];
  const float* bq = (const float*)d_in[2];
  const float* wk = (const float*)d_in[3];
  const float* bk = (const float*)d_in[4];
  const float* wv = (const float*)d_in[5];
  const float* bv = (const float*)d_in[6];
  const float* wo = (const float*)d_in[7];
  const float* bo = (const float*)d_in[8];

  f16* W  = (f16*)d_ws;                     // 4 x 65536 f16 weights
  f16* Qd = W + 262144;                     // [B,N,256]
  f16* Kd = Qd + (size_t)CB * CN * CC;      // [B,N,256]
  f16* Vt = Kd + (size_t)CB * CN * CC;      // [B,256,N]
  f16* Od = Vt + (size_t)CB * CN * CC;      // [B,N,256]

  prep_weights<<<256, 256, 0, stream>>>(wq, wk, wv, wo, W);
  qkv_kernel<<<512, 256, 0, stream>>>(x, W, W + 65536, W + 131072, bq, bk, bv, Qd, Kd, Vt);
  attn_kernel<<<512, 256, 0, stream>>>(Qd, Kd, Vt, Od);
  oproj_kernel<<<512, 256, 0, stream>>>(Od, W + 196608, bo, (float*)d_out);
}